// Round 1
// 1166.025 us; speedup vs baseline: 1.0039x; 1.0039x over previous
//
#include <hip/hip_runtime.h>
#include <cstdint>
#include <cstddef>
#include <cmath>

#define B_ 8192
#define D_ 1024
#define H_ 2048
#define O_ 1024
#define E_ 8

typedef __bf16 bf16;
typedef __bf16 bf16x8 __attribute__((ext_vector_type(8)));
typedef __bf16 bf16x4v __attribute__((ext_vector_type(4)));
typedef float f32x4 __attribute__((ext_vector_type(4)));

typedef __attribute__((address_space(1))) void gvoid;
typedef __attribute__((address_space(3))) void lvoid;

__device__ __forceinline__ void gload16(const void* g, void* l) {
  __builtin_amdgcn_global_load_lds((gvoid*)g, (lvoid*)l, 16u, 0, 0);
}

// Abramowitz-Stegun 7.1.26 rational erf, |eps| <= 1.5e-7.
__device__ __forceinline__ float fast_erff(float x) {
  float ax = __builtin_fabsf(x);
  float t = 1.f / (1.f + 0.3275911f * ax);
  float p = t * (0.254829592f +
            t * (-0.284496736f +
            t * (1.421413741f +
            t * (-1.453152027f +
            t * 1.061405429f))));
  float r = 1.f - p * __expf(-ax * ax);
  return __builtin_copysignf(r, x);
}
__device__ __forceinline__ float gelu_exact(float v) {
  return 0.5f * v * (1.f + fast_erff(v * 0.70710678118654752f));
}

// ---------------------------------------------------------------- conversions
__global__ __launch_bounds__(256) void convert_x_kernel(const float* __restrict__ x,
                                                        bf16* __restrict__ xb) {
  size_t i = (size_t)blockIdx.x * 256 + threadIdx.x;
  float4 v = ((const float4*)x)[i];
  bf16x4v o;
  o[0] = (bf16)v.x; o[1] = (bf16)v.y; o[2] = (bf16)v.z; o[3] = (bf16)v.w;
  ((bf16x4v*)xb)[i] = o;
}

// w: [E][R][C] f32 row-major  ->  wt: [E][C][R] bf16
__global__ __launch_bounds__(256) void transpose_w_kernel(const float* __restrict__ w,
                                                          bf16* __restrict__ wt,
                                                          int R, int C) {
  __shared__ float tile[32][33];
  int e = blockIdx.z;
  int c0 = blockIdx.x * 32, r0 = blockIdx.y * 32;
  int tx = threadIdx.x, ty = threadIdx.y;  // 32 x 8
  const float* we = w + (size_t)e * R * C;
  bf16* wte = wt + (size_t)e * R * C;
#pragma unroll
  for (int k = 0; k < 4; ++k) {
    int r = ty + 8 * k;
    tile[r][tx] = we[(size_t)(r0 + r) * C + c0 + tx];
  }
  __syncthreads();
#pragma unroll
  for (int k = 0; k < 4; ++k) {
    int c = ty + 8 * k;
    wte[(size_t)(c0 + c) * R + r0 + tx] = (bf16)tile[tx][c];
  }
}

// ---------------------------------------------------------------- gating
__global__ __launch_bounds__(256) void gating_kernel(const float* __restrict__ x,
                                                     const float* __restrict__ gw,
                                                     const float* __restrict__ gb,
                                                     float* __restrict__ probs,
                                                     float* __restrict__ wts,
                                                     float* __restrict__ ent) {
  int w = threadIdx.x >> 6, l = threadIdx.x & 63;
  int b = blockIdx.x * 4 + w;
  const float* xr = x + (size_t)b * D_;
  float acc[E_];
#pragma unroll
  for (int e = 0; e < E_; ++e) acc[e] = 0.f;
  for (int j = 0; j < D_ / 64; ++j) {
    int d = j * 64 + l;
    float xv = xr[d];
    const float* g = gw + (size_t)d * E_;
#pragma unroll
    for (int e = 0; e < E_; ++e) acc[e] += xv * g[e];
  }
#pragma unroll
  for (int off = 32; off; off >>= 1)
#pragma unroll
    for (int e = 0; e < E_; ++e) acc[e] += __shfl_down(acc[e], off);

  if (l == 0) {
    float lg[E_], p[E_];
    float mx = -1e30f;
#pragma unroll
    for (int e = 0; e < E_; ++e) { lg[e] = acc[e] + gb[e]; mx = fmaxf(mx, lg[e]); }
    float s = 0.f;
#pragma unroll
    for (int e = 0; e < E_; ++e) { p[e] = expf(lg[e] - mx); s += p[e]; }
    float inv = 1.f / s;
    float en = 0.f;
#pragma unroll
    for (int e = 0; e < E_; ++e) { p[e] *= inv; en -= p[e] * logf(p[e] + 1e-8f); }
    ent[b] = en;
#pragma unroll
    for (int e = 0; e < E_; ++e) probs[(size_t)b * E_ + e] = p[e];
    int idx[E_]; float ps[E_];
#pragma unroll
    for (int e = 0; e < E_; ++e) { idx[e] = e; ps[e] = p[e]; }
    for (int i = 0; i < E_ - 1; ++i)
      for (int j = 0; j < E_ - 1 - i; ++j)
        if (ps[j] < ps[j + 1]) {
          float tp = ps[j]; ps[j] = ps[j + 1]; ps[j + 1] = tp;
          int ti = idx[j]; idx[j] = idx[j + 1]; idx[j + 1] = ti;
        }
    float cum = 0.f; float mp[E_];
#pragma unroll
    for (int e = 0; e < E_; ++e) mp[e] = 0.f;
    for (int i = 0; i < E_; ++i) {
      cum += ps[i];
      bool m = (cum <= 0.9f) || (i == 0);
      if (m) mp[idx[i]] = ps[i];
    }
    float ssum = 0.f;
#pragma unroll
    for (int e = 0; e < E_; ++e) ssum += mp[e];
    float invs = 1.f / (ssum + 1e-8f);
#pragma unroll
    for (int e = 0; e < E_; ++e) wts[(size_t)b * E_ + e] = mp[e] * invs;
  }
}

// ---------------------------------------------------------------- 256^2 8-phase GEMM core
// 256x256 tile, BK=64, 512 threads (2x4 waves), per-wave 128x64 output, acc[8][4].
// LDS 128 KiB = 2 buffers x (A[256][64] | B[256][64]) bf16.
// Staging unit = K-half (256 rows x 32 K = 16 KB = 2 x gload16 per thread).
// LDS layout per K-half: row r (64 B), 16B-chunk c stored at pos c ^ ((r>>1)&3).
// Staged via linear-dest global_load_lds with PRE-SWIZZLED global source (both-sides rule);
// frag reads use pos = fc ^ ((fm>>1)&3) (lane constant) -> proven 2-lanes/bank pattern.
//
// Phase order per K-tile t (buffer p = t&1): P1=(kh0,mh0) P2=(kh0,mh1) P3=(kh1,mh0) P4=(kh1,mh1).
// Prefetch stream (dead-window safe):
//   P1 stages A.kh1(t+1) -> buf p^1 (dead since t-1 ended)
//   P2 stages B.kh1(t+1) -> buf p^1
//   P3 stages A.kh0(t+2) -> buf p   (kh0 region dead after P2's closing barrier)
//   P4 stages B.kh0(t+2) -> buf p
// One counted wait per K-tile: vmcnt(4) after P4 (leaves the 2 newest halves in flight);
// invariant: tile t+1's 4 halves are strictly older than those -> guaranteed landed.
// Drain vmcnt(0) at t = nt-2 (tail tiles issue nothing).

__device__ __forceinline__ void stage_half(const bf16* __restrict__ src, int ld,
                                           int kOff, bf16* ldsHalf,
                                           int w, int row16, int posG) {
#pragma unroll
  for (int c2 = 0; c2 < 2; ++c2) {
    const int call = w * 2 + c2;            // 0..15, wave-uniform
    const int r = call * 16 + row16;        // 0..255
    const int gchunk = posG ^ ((r >> 1) & 3);
    gload16(src + (size_t)r * ld + kOff + gchunk * 8, ldsHalf + call * 512);
  }
}

__device__ __forceinline__ void phase_pre_mfma() {
  __builtin_amdgcn_s_barrier();
  asm volatile("s_waitcnt lgkmcnt(0)" ::: "memory");
  __builtin_amdgcn_sched_barrier(0);   // rule #18: pin MFMA below the lgkm wait
  __builtin_amdgcn_s_setprio(1);
}
__device__ __forceinline__ void phase_post_mfma() {
  __builtin_amdgcn_s_setprio(0);
  __builtin_amdgcn_s_barrier();
}

#define MFMA_QUAD(MB)                                                                   \
  _Pragma("unroll") for (int m_ = 0; m_ < 4; ++m_)                                      \
  _Pragma("unroll") for (int n_ = 0; n_ < 4; ++n_)                                      \
    acc[(MB) + m_][n_] =                                                                \
        __builtin_amdgcn_mfma_f32_16x16x32_bf16(afr[m_], bfr[n_], acc[(MB) + m_][n_], 0, 0, 0);

// -------- GEMM1: h[e][row][col] = gelu(x @ w1[e] + b1[e]) * wts[row][e]; hsum atomics.
__global__ __launch_bounds__(512) void gemm1_v6_kernel(const bf16* __restrict__ xb,
                                                       const bf16* __restrict__ w1t,
                                                       const float* __restrict__ b1,
                                                       const float* __restrict__ wts,
                                                       bf16* __restrict__ h_chunk,
                                                       float* __restrict__ hsum,
                                                       int rowOffset, int Bc, int nRow) {
  __shared__ bf16 smem[65536];   // 128 KiB
  const int tid = threadIdx.x;
  const int w = tid >> 6, l = tid & 63;
  const int wm = w >> 2, wn = w & 3;            // 2 x 4 wave grid
  const int fm = l & 15, fc = l >> 4;
  const int posOff = (fc ^ ((fm >> 1) & 3)) * 8;
  const int row16 = l >> 2, posG = l & 3;

  // XCD swizzle: expert e == xcd (w1t slice 4 MB, L2-resident per XCD).
  const int flat = blockIdx.x;
  const int xcd = flat & 7, lin = flat >> 3;
  const int cb = xcd * 8 + lin / nRow;
  const int rb = lin % nRow;
  const int colBase = cb * 256;                 // fat col in [0,16384)
  const int rowGlobal = rowOffset + rb * 256;
  const int e = colBase >> 11;

  f32x4 acc[8][4];
#pragma unroll
  for (int m = 0; m < 8; ++m)
#pragma unroll
    for (int n = 0; n < 4; ++n) acc[m][n] = 0.f;

  const bf16* Ag = xb + (size_t)rowGlobal * D_;
  const bf16* Bg = w1t + (size_t)colBase * D_;

  // prologue: tile0 (A.k0,B.k0,A.k1,B.k1) then tile1 (A.k0,B.k0); wait oldest 8 (tile0).
  stage_half(Ag, D_, 0,  smem,          w, row16, posG);
  stage_half(Bg, D_, 0,  smem + 16384,  w, row16, posG);
  stage_half(Ag, D_, 32, smem + 8192,   w, row16, posG);
  stage_half(Bg, D_, 32, smem + 24576,  w, row16, posG);
  stage_half(Ag, D_, 64, smem + 32768,  w, row16, posG);
  stage_half(Bg, D_, 64, smem + 49152,  w, row16, posG);
  asm volatile("s_waitcnt vmcnt(4)" ::: "memory");
  __builtin_amdgcn_s_barrier();

  const int nt = D_ / 64;   // 16
  bf16x8 afr[4], bfr[4];
#pragma unroll 2
  for (int t = 0; t < nt; ++t) {
    const int p = t & 1;
    bf16* bufA = smem + p * 32768;
    bf16* bufB = bufA + 16384;
    bf16* nbufA = smem + (p ^ 1) * 32768;
    bf16* nbufB = nbufA + 16384;
    const bf16* laneA = bufA + (size_t)(wm * 128 + fm) * 32 + posOff;
    const bf16* laneB = bufB + (size_t)(wn * 64 + fm) * 32 + posOff;

    // ---- P1 (kh0, mh0): 8 ds_reads
#pragma unroll
    for (int n = 0; n < 4; ++n) bfr[n] = *(const bf16x8*)(laneB + n * 512);
#pragma unroll
    for (int m = 0; m < 4; ++m) afr[m] = *(const bf16x8*)(laneA + m * 512);
    if (t + 1 < nt) stage_half(Ag, D_, (t + 1) * 64 + 32, nbufA + 8192, w, row16, posG);
    phase_pre_mfma();
    MFMA_QUAD(0)
    phase_post_mfma();

    // ---- P2 (kh0, mh1): 4 ds_reads, B reused
#pragma unroll
    for (int m = 0; m < 4; ++m) afr[m] = *(const bf16x8*)(laneA + 2048 + m * 512);
    if (t + 1 < nt) stage_half(Bg, D_, (t + 1) * 64 + 32, nbufB + 8192, w, row16, posG);
    phase_pre_mfma();
    MFMA_QUAD(4)
    phase_post_mfma();

    // ---- P3 (kh1, mh0): 8 ds_reads; stage t+2 kh0 into CURRENT buffer (region dead)
#pragma unroll
    for (int n = 0; n < 4; ++n) bfr[n] = *(const bf16x8*)(laneB + 8192 + n * 512);
#pragma unroll
    for (int m = 0; m < 4; ++m) afr[m] = *(const bf16x8*)(laneA + 8192 + m * 512);
    if (t + 2 < nt) stage_half(Ag, D_, (t + 2) * 64, bufA, w, row16, posG);
    phase_pre_mfma();
    MFMA_QUAD(0)
    phase_post_mfma();

    // ---- P4 (kh1, mh1): 4 ds_reads
#pragma unroll
    for (int m = 0; m < 4; ++m) afr[m] = *(const bf16x8*)(laneA + 10240 + m * 512);
    if (t + 2 < nt) stage_half(Bg, D_, (t + 2) * 64, bufB, w, row16, posG);
    __builtin_amdgcn_s_barrier();
    asm volatile("s_waitcnt lgkmcnt(0)" ::: "memory");
    __builtin_amdgcn_sched_barrier(0);
    __builtin_amdgcn_s_setprio(1);
    MFMA_QUAD(4)
    __builtin_amdgcn_s_setprio(0);
    if (t < nt - 2) asm volatile("s_waitcnt vmcnt(4)" ::: "memory");
    else            asm volatile("s_waitcnt vmcnt(0)" ::: "memory");
    __builtin_amdgcn_s_barrier();
  }

  // ---- epilogue: gelu + wts scale; restage via LDS in 2 row-halves for coalesced stores
  __syncthreads();
  float wgt[8][4];
#pragma unroll
  for (int m = 0; m < 8; ++m)
#pragma unroll
    for (int i = 0; i < 4; ++i)
      wgt[m][i] = wts[(size_t)(rowGlobal + wm * 128 + m * 16 + fc * 4 + i) * E_ + e];

  bf16* he = h_chunk + (size_t)e * Bc * H_;
  const int hc0 = colBase & (H_ - 1);
  const int rowLocal = rb * 256;

#pragma unroll
  for (int hh = 0; hh < 2; ++hh) {
    if (wm == hh) {
#pragma unroll
      for (int n = 0; n < 4; ++n) {
        const int col = wn * 64 + n * 16 + fm;
        const float bias = b1[colBase + col];
        float csum = 0.f;
#pragma unroll
        for (int m = 0; m < 8; ++m) {
          const int rbse = m * 16 + fc * 4;
#pragma unroll
          for (int i = 0; i < 4; ++i) {
            float v = gelu_exact(acc[m][n][i] + bias);
            csum += v;
            smem[(size_t)(rbse + i) * 264 + col] = (bf16)(v * wgt[m][i]);
          }
        }
        csum += __shfl_down(csum, 32);
        csum += __shfl_down(csum, 16);
        if (fc == 0) atomicAdd(&hsum[colBase + col], csum);
      }
    }
    __syncthreads();
#pragma unroll
    for (int j = 0; j < 8; ++j) {
      const int u = j * 512 + tid;            // 128 rows x 32 chunks
      const int row = u >> 5, ch = u & 31;
      bf16x8 v = *(const bf16x8*)(smem + (size_t)row * 264 + ch * 8);
      *(bf16x8*)(he + (size_t)(rowLocal + hh * 128 + row) * H_ + hc0 + ch * 8) = v;
    }
    __syncthreads();
  }
}

// -------- GEMM2: out += sum_{e in split} h_scaled[e] @ w2t[e]; s==0 adds sum_e wts*b2.
template <int SPLIT>
__global__ __launch_bounds__(512) void gemm2_v6_kernel(const bf16* __restrict__ h_chunk,
                                                       const bf16* __restrict__ w2t,
                                                       const float* __restrict__ b2,
                                                       const float* __restrict__ wts,
                                                       float* __restrict__ out_chunk,
                                                       int rowOffset, int Bc, int nRow) {
  __shared__ bf16 smem[65536];
  const int tid = threadIdx.x;
  const int w = tid >> 6, l = tid & 63;
  const int wm = w >> 2, wn = w & 3;
  const int fm = l & 15, fc = l >> 4;
  const int posOff = (fc ^ ((fm >> 1) & 3)) * 8;
  const int row16 = l >> 2, posG = l & 3;

  const int flat = blockIdx.x;                  // 0 .. 4*nRow-1
  const int xcd = flat & 7, lin = flat >> 3;
  const int cb = xcd >> 1;                      // same col-block per XCD pair (w2t reuse)
  const int rb = (xcd & 1) * (nRow >> 1) + lin;
  const int colBase = cb * 256;
  const int rowLocal = rb * 256;
  const int s = blockIdx.y;
  constexpr int g = E_ / SPLIT;
  const int e0 = s * g;
  constexpr int nt = g * (H_ / 64);

  f32x4 acc[8][4];
#pragma unroll
  for (int m = 0; m < 8; ++m)
#pragma unroll
    for (int n = 0; n < 4; ++n) acc[m][n] = 0.f;

  const bf16* hA = h_chunk + (size_t)rowLocal * H_;
  const bf16* wB = w2t + (size_t)colBase * H_;
  const size_t strideA = (size_t)Bc * H_;
  const size_t strideB = (size_t)O_ * H_;
  auto srcA = [&](int tt) { return hA + (size_t)(e0 + (tt >> 5)) * strideA; };
  auto srcB = [&](int tt) { return wB + (size_t)(e0 + (tt >> 5)) * strideB; };
  auto koff = [&](int tt) { return (tt & 31) * 64; };

  stage_half(srcA(0), H_, koff(0),      smem,          w, row16, posG);
  stage_half(srcB(0), H_, koff(0),      smem + 16384,  w, row16, posG);
  stage_half(srcA(0), H_, koff(0) + 32, smem + 8192,   w, row16, posG);
  stage_half(srcB(0), H_, koff(0) + 32, smem + 24576,  w, row16, posG);
  stage_half(srcA(1), H_, koff(1),      smem + 32768,  w, row16, posG);
  stage_half(srcB(1), H_, koff(1),      smem + 49152,  w, row16, posG);
  asm volatile("s_waitcnt vmcnt(4)" ::: "memory");
  __builtin_amdgcn_s_barrier();

  bf16x8 afr[4], bfr[4];
#pragma unroll 2
  for (int t = 0; t < nt; ++t) {
    const int p = t & 1;
    bf16* bufA = smem + p * 32768;
    bf16* bufB = bufA + 16384;
    bf16* nbufA = smem + (p ^ 1) * 32768;
    bf16* nbufB = nbufA + 16384;
    const bf16* laneA = bufA + (size_t)(wm * 128 + fm) * 32 + posOff;
    const bf16* laneB = bufB + (size_t)(wn * 64 + fm) * 32 + posOff;

#pragma unroll
    for (int n = 0; n < 4; ++n) bfr[n] = *(const bf16x8*)(laneB + n * 512);
#pragma unroll
    for (int m = 0; m < 4; ++m) afr[m] = *(const bf16x8*)(laneA + m * 512);
    if (t + 1 < nt) stage_half(srcA(t + 1), H_, koff(t + 1) + 32, nbufA + 8192, w, row16, posG);
    phase_pre_mfma();
    MFMA_QUAD(0)
    phase_post_mfma();

#pragma unroll
    for (int m = 0; m < 4; ++m) afr[m] = *(const bf16x8*)(laneA + 2048 + m * 512);
    if (t + 1 < nt) stage_half(srcB(t + 1), H_, koff(t + 1) + 32, nbufB + 8192, w, row16, posG);
    phase_pre_mfma();
    MFMA_QUAD(4)
    phase_post_mfma();

#pragma unroll
    for (int n = 0; n < 4; ++n) bfr[n] = *(const bf16x8*)(laneB + 8192 + n * 512);
#pragma unroll
    for (int m = 0; m < 4; ++m) afr[m] = *(const bf16x8*)(laneA + 8192 + m * 512);
    if (t + 2 < nt) stage_half(srcA(t + 2), H_, koff(t + 2), bufA, w, row16, posG);
    phase_pre_mfma();
    MFMA_QUAD(0)
    phase_post_mfma();

#pragma unroll
    for (int m = 0; m < 4; ++m) afr[m] = *(const bf16x8*)(laneA + 10240 + m * 512);
    if (t + 2 < nt) stage_half(srcB(t + 2), H_, koff(t + 2), bufB, w, row16, posG);
    __builtin_amdgcn_s_barrier();
    asm volatile("s_waitcnt lgkmcnt(0)" ::: "memory");
    __builtin_amdgcn_sched_barrier(0);
    __builtin_amdgcn_s_setprio(1);
    MFMA_QUAD(4)
    __builtin_amdgcn_s_setprio(0);
    if (t < nt - 2) asm volatile("s_waitcnt vmcnt(4)" ::: "memory");
    else            asm volatile("s_waitcnt vmcnt(0)" ::: "memory");
    __builtin_amdgcn_s_barrier();
  }

  // ---- epilogue
#pragma unroll
  for (int n = 0; n < 4; ++n) {
    const int gc = colBase + wn * 64 + n * 16 + fm;
    float b2v[E_];
    if (s == 0) {
#pragma unroll
      for (int ee = 0; ee < E_; ++ee) b2v[ee] = b2[(size_t)ee * O_ + gc];
    }
#pragma unroll
    for (int m = 0; m < 8; ++m) {
      const int lrb = rowLocal + wm * 128 + m * 16 + fc * 4;
#pragma unroll
      for (int i = 0; i < 4; ++i) {
        const int lr2 = lrb + i;
        float v = acc[m][n][i];
        if (s == 0) {
          const float4* wr = (const float4*)(wts + (size_t)(rowOffset + lr2) * E_);
          float4 w0 = wr[0], w1v = wr[1];
          v += w0.x * b2v[0] + w0.y * b2v[1] + w0.z * b2v[2] + w0.w * b2v[3] +
               w1v.x * b2v[4] + w1v.y * b2v[5] + w1v.z * b2v[6] + w1v.w * b2v[7];
        }
        float* op = out_chunk + (size_t)lr2 * O_ + gc;
        if (SPLIT == 1) *op = v;
        else atomicAdd(op, v);
      }
    }
  }
}

// ---------------------------------------------------------------- fallback GEMMs (BK=32)
__device__ __forceinline__ void gemm_loop(const bf16* __restrict__ A,
                                          const bf16* __restrict__ Bt,
                                          int K, int rowBase, int colBase,
                                          bf16* lA, bf16* lB, f32x4 acc[4][4]) {
  const int tid = threadIdx.x;
  const int w = tid >> 6, l = tid & 63;
  const int wm = w >> 1, wn = w & 1;
  const int fm = l & 15, fc = l >> 4;
  const int lr = l >> 2, lc = l & 3;
  const int sr0 = (w * 2 + 0) * 16 + lr;
  const int sr1 = (w * 2 + 1) * 16 + lr;
  const int cg0 = lc ^ ((sr0 >> 1) & 3);
  const int cg1 = lc ^ ((sr1 >> 1) & 3);
  const bf16* gA0 = A + (size_t)(rowBase + sr0) * K + cg0 * 8;
  const bf16* gA1 = A + (size_t)(rowBase + sr1) * K + cg1 * 8;
  const bf16* gB0 = Bt + (size_t)(colBase + sr0) * K + cg0 * 8;
  const bf16* gB1 = Bt + (size_t)(colBase + sr1) * K + cg1 * 8;
  bf16* lA0 = lA + (w * 2 + 0) * 512;
  bf16* lA1 = lA + (w * 2 + 1) * 512;
  bf16* lB0 = lB + (w * 2 + 0) * 512;
  bf16* lB1 = lB + (w * 2 + 1) * 512;

  for (int k0 = 0; k0 < K; k0 += 32) {
    __syncthreads();
    gload16(gA0 + k0, lA0);
    gload16(gA1 + k0, lA1);
    gload16(gB0 + k0, lB0);
    gload16(gB1 + k0, lB1);
    __syncthreads();

    bf16x8 af[4], bb[4];
#pragma unroll
    for (int mt = 0; mt < 4; ++mt) {
      int r = wm * 64 + mt * 16 + fm;
      af[mt] = *(const bf16x8*)(lA + (size_t)(r * 4 + (fc ^ ((r >> 1) & 3))) * 8);
    }
#pragma unroll
    for (int nt = 0; nt < 4; ++nt) {
      int r = wn * 64 + nt * 16 + fm;
      bb[nt] = *(const bf16x8*)(lB + (size_t)(r * 4 + (fc ^ ((r >> 1) & 3))) * 8);
    }
#pragma unroll
    for (int mt = 0; mt < 4; ++mt)
#pragma unroll
      for (int nt = 0; nt < 4; ++nt)
        acc[mt][nt] = __builtin_amdgcn_mfma_f32_16x16x32_bf16(af[mt], bb[nt], acc[mt][nt], 0, 0, 0);
  }
}

__global__ __launch_bounds__(256) void gemm1_gelu_kernel(const bf16* __restrict__ xb,
                                                         const bf16* __restrict__ w1te,
                                                         const float* __restrict__ b1e,
                                                         bf16* __restrict__ h) {
  __shared__ bf16 lA[128 * 32];
  __shared__ bf16 lB[128 * 32];
  f32x4 acc[4][4];
#pragma unroll
  for (int mt = 0; mt < 4; ++mt)
#pragma unroll
    for (int nt = 0; nt < 4; ++nt) acc[mt][nt] = 0.f;

  int rowBase = blockIdx.y * 128, colBase = blockIdx.x * 128;
  gemm_loop(xb, w1te, D_, rowBase, colBase, lA, lB, acc);

  const int w = threadIdx.x >> 6, l = threadIdx.x & 63;
  const int wm = w >> 1, wn = w & 1;
#pragma unroll
  for (int mt = 0; mt < 4; ++mt)
#pragma unroll
    for (int nt = 0; nt < 4; ++nt) {
      int gc = colBase + wn * 64 + nt * 16 + (l & 15);
      float bias = b1e[gc];
#pragma unroll
      for (int i = 0; i < 4; ++i) {
        int gr = rowBase + wm * 64 + mt * 16 + (l >> 4) * 4 + i;
        float v = gelu_exact(acc[mt][nt][i] + bias);
        h[(size_t)gr * H_ + gc] = (bf16)v;
      }
    }
}

__global__ __launch_bounds__(256) void gemm2_fused_kernel(const bf16* __restrict__ h,
                                                          const bf16* __restrict__ w2te,
                                                          const float* __restrict__ b2e,
                                                          const float* __restrict__ wts,
                                                          int e,
                                                          float* __restrict__ out,
                                                          float* __restrict__ esum) {
  __shared__ bf16 lA[128 * 32];
  __shared__ bf16 lB[128 * 32];
  f32x4 acc[4][4];
#pragma unroll
  for (int mt = 0; mt < 4; ++mt)
#pragma unroll
    for (int nt = 0; nt < 4; ++nt) acc[mt][nt] = 0.f;

  int rowBase = blockIdx.y * 128, colBase = blockIdx.x * 128;
  gemm_loop(h, w2te, H_, rowBase, colBase, lA, lB, acc);

  const int w = threadIdx.x >> 6, l = threadIdx.x & 63;
  const int wm = w >> 1, wn = w & 1;
#pragma unroll
  for (int nt = 0; nt < 4; ++nt) {
    int gc = colBase + wn * 64 + nt * 16 + (l & 15);
    float bias = b2e[gc];
    float csum = 0.f;
#pragma unroll
    for (int mt = 0; mt < 4; ++mt) {
      int grb = rowBase + wm * 64 + mt * 16 + (l >> 4) * 4;
#pragma unroll
      for (int i = 0; i < 4; ++i) {
        int gr = grb + i;
        float v = acc[mt][nt][i] + bias;
        csum += v;
        float wgt = wts[(size_t)gr * E_ + e];
        float* op = out + (size_t)gr * O_ + gc;
        *op += wgt * v;
      }
    }
    csum += __shfl_down(csum, 32);
    csum += __shfl_down(csum, 16);
    if ((l >> 4) == 0) atomicAdd(&esum[(size_t)e * O_ + gc], csum);
  }
}

// ---------------------------------------------------------------- losses
// MODE 0: expert_mean = esum/B (bias included). MODE 1: esum/B + b2.
template <int MODE>
__global__ __launch_bounds__(256) void scalars_kernel(const float* __restrict__ probs,
                                                      const float* __restrict__ ent,
                                                      const float* __restrict__ esum,
                                                      const float* __restrict__ b2,
                                                      float* __restrict__ outs) {
  __shared__ float red[256];
  __shared__ float Vsh[E_][O_ + 8];
  __shared__ float mp_sh[E_], norm_sh[E_];
  __shared__ float gram[E_][E_];
  int t = threadIdx.x;

  float s = 0.f;
  for (int i = t; i < B_; i += 256) s += ent[i];
  red[t] = s; __syncthreads();
  for (int off = 128; off; off >>= 1) { if (t < off) red[t] += red[t + off]; __syncthreads(); }
  if (t == 0) outs[0] = red[0] / (float)B_;
  __syncthreads();

  float mp[E_];
#pragma unroll
  for (int e = 0; e < E_; ++e) mp[e] = 0.f;
  for (int i = t; i < B_; i += 256) {
#pragma unroll
    for (int e = 0; e < E_; ++e) mp[e] += probs[(size_t)i * E_ + e];
  }
  for (int e = 0; e < E_; ++e) {
    red[t] = mp[e]; __syncthreads();
    for (int off = 128; off; off >>= 1) { if (t < off) red[t] += red[t + off]; __syncthreads(); }
    if (t == 0) mp_sh[e] = red[0] / (float)B_;
    __syncthreads();
  }

  for (int e = 0; e < E_; ++e) {
    float ss = 0.f;
    for (int o = t; o < O_; o += 256) {
      float m = esum[(size_t)e * O_ + o] / (float)B_;
      if (MODE == 1) m += b2[(size_t)e * O_ + o];
      ss += m * m;
    }
    red[t] = ss; __syncthreads();
    for (int off = 128; off; off >>= 1) { if (t < off) red[t] += red[t + off]; __syncthreads(); }
    if (t == 0) norm_sh[e] = sqrtf(red[0]) + 1e-6f;
    __syncthreads();
  }

  for (int e = 0; e < E_; ++e)
    for (int o = t; o < O_; o += 256) {
      float m = esum[(size_t)e * O_ + o] / (float)B_;
      if (MODE == 1) m += b2[(size_t)e * O_ + o];
      Vsh[e][o] = mp_sh[e] * m / norm_sh[e];
    }
  __syncthreads();

  if (t < 64) {
    int i = t >> 3, j = t & 7;
    float g = 0.f;
    for (int o = 0; o < O_; ++o) g += Vsh[i][o] * Vsh[j][o];
    if (i == j) g += 1e-6f;
    gram[i][j] = g;
  }
  __syncthreads();

  if (t == 0) {
    double a[E_][E_];
    for (int i = 0; i < E_; ++i) for (int j = 0; j < E_; ++j) a[i][j] = (double)gram[i][j];
    double ld = 0.0;
    for (int k = 0; k < E_; ++k) {
      int p = k; double mx = fabs(a[k][k]);
      for (int i = k + 1; i < E_; ++i) if (fabs(a[i][k]) > mx) { mx = fabs(a[i][k]); p = i; }
      if (p != k) for (int j = 0; j < E_; ++j) { double tmp = a[k][j]; a[k][j] = a[p][j]; a[p][j] = tmp; }
      ld += log(fabs(a[k][k]));
      double inv = 1.0 / a[k][k];
      for (int i = k + 1; i < E_; ++i) {
        double f = a[i][k] * inv;
        for (int j = k; j < E_; ++j) a[i][j] -= f * a[k][j];
      }
    }
    outs[1] = (float)(-ld);
  }
}

// esum2[e][o] = hsum[e,:] . w2[e,:,o]
__global__ __launch_bounds__(256) void esum_kernel(const float* __restrict__ hsum,
                                                   const float* __restrict__ w2,
                                                   float* __restrict__ esum2) {
  int e = blockIdx.y;
  int o = blockIdx.x * 256 + threadIdx.x;
  const float* w2e = w2 + (size_t)e * H_ * O_;
  const float* hs = hsum + (size_t)e * H_;
  float a0 = 0.f, a1 = 0.f;
  for (int h = 0; h < H_; h += 2) {
    a0 += hs[h] * w2e[(size_t)h * O_ + o];
    a1 += hs[h + 1] * w2e[(size_t)(h + 1) * O_ + o];
  }
  esum2[(size_t)e * O_ + o] = a0 + a1;
}

// ---------------------------------------------------------------- launch
extern "C" void kernel_launch(void* const* d_in, const int* in_sizes, int n_in,
                              void* d_out, int out_size, void* d_ws, size_t ws_size,
                              hipStream_t stream) {
  const float* x  = (const float*)d_in[0];
  const float* gw = (const float*)d_in[1];
  const float* gb = (const float*)d_in[2];
  const float* w1 = (const float*)d_in[3];
  const float* b1 = (const float*)d_in[4];
  const float* w2 = (const float*)d_in[5];
  const float* b2 = (const float*)d_in[6];
  float* out = (float*)d_out;

  char* ws = (char*)d_ws;
  size_t need = 0;
  bf16* xb    = (bf16*)(ws + need); need += (size_t)B_ * D_ * 2;
  bf16* w1t   = (bf16*)(ws + need); need += (size_t)E_ * D_ * H_ * 2;
  bf16* w2t   = (bf16*)(ws + need); need += (size_t)E_ * H_ * O_ * 2;
  float* wts  = (float*)(ws + need); need += (size_t)B_ * E_ * 4;
  float* probs= (float*)(ws + need); need += (size_t)B_ * E_ * 4;
  float* ent  = (float*)(ws + need); need += (size_t)B_ * 4;
  float* hsum = (float*)(ws + need); need += (size_t)E_ * H_ * 4;
  float* esum = (float*)(ws + need); need += (size_t)E_ * O_ * 4;
  size_t need_common = need;
  bf16* h_chunk = (bf16*)(ws + need);

  int NC = 0;
  for (int nc = 1; nc <= 8; nc <<= 1) {
    size_t tot = need_common + (size_t)E_ * (B_ / nc) * H_ * 2;
    if (ws_size >= tot) { NC = nc; break; }
  }

  convert_x_kernel<<<(B_ * D_ / 4) / 256, 256, 0, stream>>>(x, xb);
  transpose_w_kernel<<<dim3(H_ / 32, D_ / 32, E_), dim3(32, 8), 0, stream>>>(w1, w1t, D_, H_);
  transpose_w_kernel<<<dim3(O_ / 32, H_ / 32, E_), dim3(32, 8), 0, stream>>>(w2, w2t, H_, O_);
  gating_kernel<<<B_ / 4, 256, 0, stream>>>(x, gw, gb, probs, wts, ent);

  if (NC > 0) {
    const int Bc = B_ / NC;
    const int nRow = Bc / 256;
    const int SPLIT = (NC == 1) ? 2 : (NC == 2) ? 4 : 8;
    hipMemsetAsync(hsum, 0, (size_t)E_ * H_ * sizeof(float), stream);
    hipMemsetAsync(out, 0, (size_t)B_ * O_ * sizeof(float), stream);
    for (int c = 0; c < NC; ++c) {
      int rowOffset = c * Bc;
      gemm1_v6_kernel<<<64 * nRow, 512, 0, stream>>>(
          xb, w1t, b1, wts, h_chunk, hsum, rowOffset, Bc, nRow);
      float* out_chunk = out + (size_t)rowOffset * O_;
      dim3 g2(4 * nRow, SPLIT);
      switch (SPLIT) {
        case 2: gemm2_v6_kernel<2><<<g2, 512, 0, stream>>>(h_chunk, w2t, b2, wts, out_chunk, rowOffset, Bc, nRow); break;
        case 4: gemm2_v6_kernel<4><<<g2, 512, 0, stream>>>(h_chunk, w2t, b2, wts, out_chunk, rowOffset, Bc, nRow); break;
        case 8: gemm2_v6_kernel<8><<<g2, 512, 0, stream>>>(h_chunk, w2t, b2, wts, out_chunk, rowOffset, Bc, nRow); break;
      }
    }
    esum_kernel<<<dim3(O_ / 256, E_), 256, 0, stream>>>(hsum, w2, esum);
    scalars_kernel<1><<<1, 256, 0, stream>>>(probs, ent, esum, b2, out + (size_t)B_ * O_);
  } else {
    bf16* he = (bf16*)(ws + need_common);
    if (ws_size < need_common + (size_t)B_ * H_ * 2) return;
    hipMemsetAsync(out, 0, (size_t)B_ * O_ * sizeof(float), stream);
    hipMemsetAsync(esum, 0, (size_t)E_ * O_ * sizeof(float), stream);
    for (int e = 0; e < E_; ++e) {
      gemm1_gelu_kernel<<<dim3(H_ / 128, B_ / 128), 256, 0, stream>>>(
          xb, w1t + (size_t)e * H_ * D_, b1 + (size_t)e * H_, he);
      gemm2_fused_kernel<<<dim3(O_ / 128, B_ / 128), 256, 0, stream>>>(
          he, w2t + (size_t)e * O_ * H_, b2 + (size_t)e * O_, wts, e, out, esum);
    }
    scalars_kernel<0><<<1, 256, 0, stream>>>(probs, ent, esum, b2, out + (size_t)B_ * O_);
  }
}